// Round 17
// baseline (58.438 us; speedup 1.0000x reference)
//
#include <hip/hip_runtime.h>
#include <math.h>

#define B 4
#define TQ 512
#define TV 1024
#define DQ 256
#define DV 256
#define UNITS 64
#define NQROW (B * TQ)   // 2048
#define NKROW (B * TV)   // 4096

#define CEXP  2.885390081777927f    // 2*log2(e): exp(2x) == exp2(CEXP*x)
#define LOG2E 1.4426950408889634f

__device__ __forceinline__ float fast_exp2(float x) {
#if __has_builtin(__builtin_amdgcn_exp2f)
    return __builtin_amdgcn_exp2f(x);
#else
    return __expf(0.6931471805599453f * x);
#endif
}

__device__ __forceinline__ float wave_sum(float v) {
    #pragma unroll
    for (int off = 32; off > 0; off >>= 1)
        v += __shfl_xor(v, off, 64);
    return v;
}

__device__ __forceinline__ unsigned short f2bf(float f) {   // RNE
    unsigned int b = __float_as_uint(f);
    return (unsigned short)((b + 0x7fffu + ((b >> 16) & 1u)) >> 16);
}

// ---- projections (known-good) + bf16 value emission ----
#define RPB 8
__global__ __launch_bounds__(256) void proj_kernel(
        const float* __restrict__ query, const float* __restrict__ value,
        const float* __restrict__ w1, const float* __restrict__ w2,
        float* __restrict__ Eq, float* __restrict__ EkT,
        unsigned short* __restrict__ vbf) {
    __shared__ float rows[RPB][DQ];            // 8 KB
    __shared__ float part[4][RPB][UNITS + 2];  // padded vs bank conflicts
    const int tid = threadIdx.x;
    const int u   = tid & 63;
    const int wid = tid >> 6;                  // 0..3 -> d-range
    const int row0 = blockIdx.x * RPB;
    const bool isq = row0 < NQROW;
    const float* in = isq ? query + (size_t)row0 * DQ
                          : value + (size_t)(row0 - NQROW) * DQ;
    const float* w  = isq ? w1 : w2;

    {   // stage 8 rows (2048 floats) coalesced
        const float4* src = (const float4*)in;
        float4* dst = (float4*)&rows[0][0];
        dst[tid]       = src[tid];
        dst[tid + 256] = src[tid + 256];
    }
    __syncthreads();

    float a[RPB] = {};
    const int c0 = wid * 16;
    #pragma unroll 4
    for (int ci = 0; ci < 16; ++ci) {
        const int c = c0 + ci;
        const float w0v = w[(4 * c + 0) * UNITS + u];
        const float w1v = w[(4 * c + 1) * UNITS + u];
        const float w2v = w[(4 * c + 2) * UNITS + u];
        const float w3v = w[(4 * c + 3) * UNITS + u];
        #pragma unroll
        for (int r = 0; r < RPB; ++r) {
            const float4 t = *(const float4*)&rows[r][4 * c];
            a[r] = fmaf(t.x, w0v, a[r]);
            a[r] = fmaf(t.y, w1v, a[r]);
            a[r] = fmaf(t.z, w2v, a[r]);
            a[r] = fmaf(t.w, w3v, a[r]);
        }
    }
    #pragma unroll
    for (int r = 0; r < RPB; ++r)
        part[wid][r][u] = a[r];
    __syncthreads();

    if (isq) {
        #pragma unroll
        for (int h = 0; h < 2; ++h) {
            const int p = tid + h * 256;
            const int row = p >> 6, uu = p & 63;
            const float s = (part[0][row][uu] + part[1][row][uu]) +
                            (part[2][row][uu] + part[3][row][uu]);
            Eq[(size_t)(row0 + row) * UNITS + uu] = fast_exp2(CEXP * s);
        }
    } else {
        #pragma unroll
        for (int h = 0; h < 2; ++h) {
            const int p = tid + h * 256;
            const int uu = p >> 3, r = p & 7;
            const float s = (part[0][r][uu] + part[1][r][uu]) +
                            (part[2][r][uu] + part[3][r][uu]);
            EkT[(size_t)uu * NKROW + (row0 - NQROW) + r] = fast_exp2(CEXP * s);
        }
        // bf16 copy of the 8 staged value rows (coalesced 16B/thread)
        const float* rf = &rows[0][0];
        const int base = tid * 8;
        uint4 pk;
        pk.x = (unsigned)f2bf(rf[base + 0]) | ((unsigned)f2bf(rf[base + 1]) << 16);
        pk.y = (unsigned)f2bf(rf[base + 2]) | ((unsigned)f2bf(rf[base + 3]) << 16);
        pk.z = (unsigned)f2bf(rf[base + 4]) | ((unsigned)f2bf(rf[base + 5]) << 16);
        pk.w = (unsigned)f2bf(rf[base + 6]) | ((unsigned)f2bf(rf[base + 7]) << 16);
        *(uint4*)(vbf + (size_t)(row0 - NQROW) * DV + base) = pk;
    }
}

// ---- fused scores + softmax + context: QB=2, 256 thr, grid 1024 (4 blk/CU) -
#define QB 2
#define SNW 4
__global__ __launch_bounds__(256) void sc_kernel(
        const float* __restrict__ Eq,      // [NQROW][UNITS]
        const float* __restrict__ EkT,     // [UNITS][NKROW]
        const float* __restrict__ scale,   // [UNITS]
        const unsigned short* __restrict__ vbf,  // [B][TV][DV] bf16
        float* __restrict__ out_attn,      // [NQROW][TV]
        float* __restrict__ out_ctx) {     // [NQROW][DV]
    __shared__ float a_lds[QB][TV];        // 8 KB (reused as reduce buf)
    __shared__ float q_lds[QB][UNITS];
    __shared__ float s_lds[UNITS];
    __shared__ float reds[QB][SNW];

    const int tid = threadIdx.x, lane = tid & 63, wid = tid >> 6;
    int bid = blockIdx.x;
    bid = (bid & 7) * ((NQROW / QB) >> 3) + (bid >> 3);   // XCD swizzle, bijective
    const int b  = bid / (TQ / QB);
    const int q0 = (bid % (TQ / QB)) * QB;

    if (tid < QB * UNITS)
        q_lds[tid >> 6][tid & 63] =
            Eq[(size_t)(b * TQ + q0 + (tid >> 6)) * UNITS + (tid & 63)];
    else if (tid < QB * UNITS + UNITS)
        s_lds[tid - QB * UNITS] = scale[tid - QB * UNITS];
    __syncthreads();

    // ---- phase A: scores; thread owns v = {4tid..4tid+3} (float4 loads) ----
    const float* ekc = EkT + (size_t)b * TV + 4 * tid;
    float4 acc[QB];
    #pragma unroll
    for (int q = 0; q < QB; ++q) { acc[q].x = acc[q].y = acc[q].z = acc[q].w = 0.f; }

    #pragma unroll 4
    for (int u4 = 0; u4 < UNITS / 4; ++u4) {
        const float4 ekA = *(const float4*)(ekc + (size_t)(4 * u4 + 0) * NKROW);
        const float4 ekB = *(const float4*)(ekc + (size_t)(4 * u4 + 1) * NKROW);
        const float4 ekC = *(const float4*)(ekc + (size_t)(4 * u4 + 2) * NKROW);
        const float4 ekD = *(const float4*)(ekc + (size_t)(4 * u4 + 3) * NKROW);
        const float4 s4 = *(const float4*)(s_lds + 4 * u4);
        #pragma unroll
        for (int q = 0; q < QB; ++q) {
            const float4 eq = *(const float4*)(&q_lds[q][4 * u4]);
            #define EVAL(comp)                                                   \
            {                                                                    \
                float t0 = fmaf(eq.x, ekA.comp, 1.f);                            \
                float t1 = fmaf(eq.y, ekB.comp, 1.f);                            \
                float t2 = fmaf(eq.z, ekC.comp, 1.f);                            \
                float t3 = fmaf(eq.w, ekD.comp, 1.f);                            \
                float p01 = t0 * t1, p23 = t2 * t3;                              \
                float A  = fmaf(s4.y, t0, s4.x * t1);                            \
                float Bq = fmaf(s4.w, t2, s4.z * t3);                            \
                float num = fmaf(Bq, p01, A * p23);                              \
                float r = __builtin_amdgcn_rcpf(p01 * p23);                      \
                acc[q].comp = fmaf(num, r, acc[q].comp);                         \
            }
            EVAL(x) EVAL(y) EVAL(z) EVAL(w)
            #undef EVAL
        }
    }

    // ---- softmax (no-max, range-safe) + attn write + LDS stage ----
    float4 e[QB];
    #pragma unroll
    for (int q = 0; q < QB; ++q) {
        e[q].x = fast_exp2(-2.f * LOG2E * acc[q].x);
        e[q].y = fast_exp2(-2.f * LOG2E * acc[q].y);
        e[q].z = fast_exp2(-2.f * LOG2E * acc[q].z);
        e[q].w = fast_exp2(-2.f * LOG2E * acc[q].w);
        float s = wave_sum((e[q].x + e[q].y) + (e[q].z + e[q].w));
        if (lane == 0) reds[q][wid] = s;
    }
    __syncthreads();
    #pragma unroll
    for (int q = 0; q < QB; ++q) {
        float ss = (reds[q][0] + reds[q][1]) + (reds[q][2] + reds[q][3]);
        const float inv = __builtin_amdgcn_rcpf(ss);
        float4 o;
        o.x = e[q].x * inv; o.y = e[q].y * inv;
        o.z = e[q].z * inv; o.w = e[q].w * inv;
        *(float4*)(&a_lds[q][4 * tid]) = o;
        *(float4*)(out_attn + (size_t)(b * TQ + q0 + q) * TV + 4 * tid) = o;
    }
    __syncthreads();

    // ---- phase B: thread owns (4 d-cols, 2 q-rows, 256-v range), bf16 value -
    const int vq = tid >> 6;               // 0..3 -> v-range (one wave each)
    const int dp = tid & 63;               // d-quad index
    const int d0 = dp * 4;
    const unsigned short* vb = vbf + ((size_t)b * TV + vq * 256) * DV + d0;
    float4 c[QB];
    #pragma unroll
    for (int q = 0; q < QB; ++q) { c[q].x = c[q].y = c[q].z = c[q].w = 0.f; }

    #pragma unroll 2
    for (int v4 = 0; v4 < 64; ++v4) {
        const int v = vq * 256 + v4 * 4;
        const float4 a0 = *(const float4*)&a_lds[0][v];
        const float4 a1 = *(const float4*)&a_lds[1][v];
        #define STEP(j, comp)                                                    \
        {                                                                        \
            const ushort4 wv = *(const ushort4*)(vb + (size_t)(v4 * 4 + j) * DV);\
            const float v0 = __uint_as_float((unsigned)wv.x << 16);              \
            const float v1 = __uint_as_float((unsigned)wv.y << 16);              \
            const float v2 = __uint_as_float((unsigned)wv.z << 16);              \
            const float v3 = __uint_as_float((unsigned)wv.w << 16);              \
            c[0].x = fmaf(a0.comp, v0, c[0].x); c[0].y = fmaf(a0.comp, v1, c[0].y); \
            c[0].z = fmaf(a0.comp, v2, c[0].z); c[0].w = fmaf(a0.comp, v3, c[0].w); \
            c[1].x = fmaf(a1.comp, v0, c[1].x); c[1].y = fmaf(a1.comp, v1, c[1].y); \
            c[1].z = fmaf(a1.comp, v2, c[1].z); c[1].w = fmaf(a1.comp, v3, c[1].w); \
        }
        STEP(0, x) STEP(1, y) STEP(2, z) STEP(3, w)
        #undef STEP
    }
    __syncthreads();   // all a_lds reads done; reuse as reduce buffer

    // reduce partials across the 4 v-groups (wave 0 finishes)
    float* red = &a_lds[0][0];             // 3 * 2q * 64dp * 4 floats = 6 KB
    if (vq != 0) {
        float* r = red + (((vq - 1) * QB) * 64 + dp) * 4;
        #pragma unroll
        for (int q = 0; q < QB; ++q)
            *(float4*)(r + q * 64 * 4) = c[q];
    }
    __syncthreads();
    if (vq == 0) {
        #pragma unroll
        for (int g = 0; g < 3; ++g) {
            const float* r = red + ((g * QB) * 64 + dp) * 4;
            #pragma unroll
            for (int q = 0; q < QB; ++q) {
                const float4 t = *(const float4*)(r + q * 64 * 4);
                c[q].x += t.x; c[q].y += t.y; c[q].z += t.z; c[q].w += t.w;
            }
        }
        #pragma unroll
        for (int q = 0; q < QB; ++q)
            *(float4*)(out_ctx + (size_t)(b * TQ + q0 + q) * DV + d0) = c[q];
    }
}

extern "C" void kernel_launch(void* const* d_in, const int* in_sizes, int n_in,
                              void* d_out, int out_size, void* d_ws, size_t ws_size,
                              hipStream_t stream) {
    const float* query = (const float*)d_in[0];
    const float* value = (const float*)d_in[1];
    const float* w1    = (const float*)d_in[2];
    const float* w2    = (const float*)d_in[3];
    const float* scale = (const float*)d_in[4];

    float* out      = (float*)d_out;
    float* out_ctx  = out;                         // [NQROW*DV]
    float* out_attn = out + (size_t)NQROW * DV;    // [NQROW*TV]

    float* Eq  = (float*)d_ws;                         // NQROW*UNITS floats
    float* EkT = Eq + (size_t)NQROW * UNITS;           // UNITS*NKROW floats
    unsigned short* vbf = (unsigned short*)(EkT + (size_t)UNITS * NKROW);

    proj_kernel<<<dim3((NQROW + NKROW) / RPB), 256, 0, stream>>>(
        query, value, w1, w2, Eq, EkT, vbf);
    sc_kernel<<<dim3(NQROW / QB), 256, 0, stream>>>(
        Eq, EkT, scale, vbf, out_attn, out_ctx);
}

// Round 18
// 43.462 us; speedup vs baseline: 1.3446x; 1.3446x over previous
//
#include <hip/hip_runtime.h>
#include <math.h>

#define B 4
#define TQ 512
#define TV 1024
#define DQ 256
#define DV 256
#define UNITS 64
#define NQROW (B * TQ)   // 2048
#define NKROW (B * TV)   // 4096

#define CEXP  2.885390081777927f    // 2*log2(e): exp(2x) == exp2(CEXP*x)
#define LOG2E 1.4426950408889634f

__device__ __forceinline__ float fast_exp2(float x) {
#if __has_builtin(__builtin_amdgcn_exp2f)
    return __builtin_amdgcn_exp2f(x);
#else
    return __expf(0.6931471805599453f * x);
#endif
}

__device__ __forceinline__ float wave_sum(float v) {
    #pragma unroll
    for (int off = 32; off > 0; off >>= 1)
        v += __shfl_xor(v, off, 64);
    return v;
}

__device__ __forceinline__ unsigned short f2bf(float f) {   // RNE
    unsigned int b = __float_as_uint(f);
    return (unsigned short)((b + 0x7fffu + ((b >> 16) & 1u)) >> 16);
}

// ---- projections (known-good) + bf16 value emission ----
#define RPB 8
__global__ __launch_bounds__(256) void proj_kernel(
        const float* __restrict__ query, const float* __restrict__ value,
        const float* __restrict__ w1, const float* __restrict__ w2,
        float* __restrict__ Eq, float* __restrict__ EkT,
        unsigned short* __restrict__ vbf) {
    __shared__ float rows[RPB][DQ];            // 8 KB
    __shared__ float part[4][RPB][UNITS + 2];  // padded vs bank conflicts
    const int tid = threadIdx.x;
    const int u   = tid & 63;
    const int wid = tid >> 6;                  // 0..3 -> d-range
    const int row0 = blockIdx.x * RPB;
    const bool isq = row0 < NQROW;
    const float* in = isq ? query + (size_t)row0 * DQ
                          : value + (size_t)(row0 - NQROW) * DQ;
    const float* w  = isq ? w1 : w2;

    {   // stage 8 rows (2048 floats) coalesced
        const float4* src = (const float4*)in;
        float4* dst = (float4*)&rows[0][0];
        dst[tid]       = src[tid];
        dst[tid + 256] = src[tid + 256];
    }
    __syncthreads();

    float a[RPB] = {};
    const int c0 = wid * 16;
    #pragma unroll 4
    for (int ci = 0; ci < 16; ++ci) {
        const int c = c0 + ci;
        const float w0v = w[(4 * c + 0) * UNITS + u];
        const float w1v = w[(4 * c + 1) * UNITS + u];
        const float w2v = w[(4 * c + 2) * UNITS + u];
        const float w3v = w[(4 * c + 3) * UNITS + u];
        #pragma unroll
        for (int r = 0; r < RPB; ++r) {
            const float4 t = *(const float4*)&rows[r][4 * c];
            a[r] = fmaf(t.x, w0v, a[r]);
            a[r] = fmaf(t.y, w1v, a[r]);
            a[r] = fmaf(t.z, w2v, a[r]);
            a[r] = fmaf(t.w, w3v, a[r]);
        }
    }
    #pragma unroll
    for (int r = 0; r < RPB; ++r)
        part[wid][r][u] = a[r];
    __syncthreads();

    if (isq) {
        #pragma unroll
        for (int h = 0; h < 2; ++h) {
            const int p = tid + h * 256;
            const int row = p >> 6, uu = p & 63;
            const float s = (part[0][row][uu] + part[1][row][uu]) +
                            (part[2][row][uu] + part[3][row][uu]);
            Eq[(size_t)(row0 + row) * UNITS + uu] = fast_exp2(CEXP * s);
        }
    } else {
        #pragma unroll
        for (int h = 0; h < 2; ++h) {
            const int p = tid + h * 256;
            const int uu = p >> 3, r = p & 7;
            const float s = (part[0][r][uu] + part[1][r][uu]) +
                            (part[2][r][uu] + part[3][r][uu]);
            EkT[(size_t)uu * NKROW + (row0 - NQROW) + r] = fast_exp2(CEXP * s);
        }
        // bf16 copy of the 8 staged value rows (coalesced 16B/thread)
        const float* rf = &rows[0][0];
        const int base = tid * 8;
        uint4 pk;
        pk.x = (unsigned)f2bf(rf[base + 0]) | ((unsigned)f2bf(rf[base + 1]) << 16);
        pk.y = (unsigned)f2bf(rf[base + 2]) | ((unsigned)f2bf(rf[base + 3]) << 16);
        pk.z = (unsigned)f2bf(rf[base + 4]) | ((unsigned)f2bf(rf[base + 5]) << 16);
        pk.w = (unsigned)f2bf(rf[base + 6]) | ((unsigned)f2bf(rf[base + 7]) << 16);
        *(uint4*)(vbf + (size_t)(row0 - NQROW) * DV + base) = pk;
    }
}

// ---- fused scores + softmax + context: QB=4, 512 thr, u-split phase A ----
// grid = 512 (2 blocks/CU, 16 waves/CU). Waves 0-3: u in [0,32); waves 4-7:
// u in [32,64); partial accs combined via LDS. Phase B: 8 v-ranges.
#define QB 4
__global__ __launch_bounds__(512) void sc_kernel(
        const float* __restrict__ Eq,      // [NQROW][UNITS]
        const float* __restrict__ EkT,     // [UNITS][NKROW]
        const float* __restrict__ scale,   // [UNITS]
        const unsigned short* __restrict__ vbf,  // [B][TV][DV] bf16
        float* __restrict__ out_attn,      // [NQROW][TV]
        float* __restrict__ out_ctx) {     // [NQROW][DV]
    __shared__ float pool[QB * TV + 256 * QB * 4];   // 32 KB
    __shared__ float q_lds[QB][UNITS];
    __shared__ float s_lds[UNITS];
    __shared__ float reds[QB][4];

    float* a_lds = pool;                       // [QB][TV] attn stage
    float4* scr  = (float4*)(pool + QB * TV);  // [256][QB] u-split partials

    const int tid = threadIdx.x, lane = tid & 63, wid = tid >> 6;
    int bid = blockIdx.x;
    bid = (bid & 7) * ((NQROW / QB) >> 3) + (bid >> 3);   // XCD swizzle, bijective
    const int b  = bid / (TQ / QB);
    const int q0 = (bid % (TQ / QB)) * QB;

    if (tid < QB * UNITS)
        q_lds[tid >> 6][tid & 63] =
            Eq[(size_t)(b * TQ + q0 + (tid >> 6)) * UNITS + (tid & 63)];
    else if (tid < QB * UNITS + UNITS)
        s_lds[tid - QB * UNITS] = scale[tid - QB * UNITS];
    __syncthreads();

    // ---- phase A: u-split scores; thread owns v = {4vt..4vt+3} ----
    const int uh = tid >> 8;               // 0/1 -> u-half
    const int vt = tid & 255;
    const int ub = uh * 32;                // u base
    const float* ekc = EkT + (size_t)b * TV + 4 * vt + (size_t)ub * NKROW;
    float4 acc[QB];
    #pragma unroll
    for (int q = 0; q < QB; ++q) { acc[q].x = acc[q].y = acc[q].z = acc[q].w = 0.f; }

    #pragma unroll 2
    for (int u4 = 0; u4 < 8; ++u4) {
        const float4 ekA = *(const float4*)(ekc + (size_t)(4 * u4 + 0) * NKROW);
        const float4 ekB = *(const float4*)(ekc + (size_t)(4 * u4 + 1) * NKROW);
        const float4 ekC = *(const float4*)(ekc + (size_t)(4 * u4 + 2) * NKROW);
        const float4 ekD = *(const float4*)(ekc + (size_t)(4 * u4 + 3) * NKROW);
        const float4 s4 = *(const float4*)(s_lds + ub + 4 * u4);
        #pragma unroll
        for (int q = 0; q < QB; ++q) {
            const float4 eq = *(const float4*)(&q_lds[q][ub + 4 * u4]);
            #define EVAL(comp)                                                   \
            {                                                                    \
                float t0 = fmaf(eq.x, ekA.comp, 1.f);                            \
                float t1 = fmaf(eq.y, ekB.comp, 1.f);                            \
                float t2 = fmaf(eq.z, ekC.comp, 1.f);                            \
                float t3 = fmaf(eq.w, ekD.comp, 1.f);                            \
                float p01 = t0 * t1, p23 = t2 * t3;                              \
                float A  = fmaf(s4.y, t0, s4.x * t1);                            \
                float Bq = fmaf(s4.w, t2, s4.z * t3);                            \
                float num = fmaf(Bq, p01, A * p23);                              \
                float r = __builtin_amdgcn_rcpf(p01 * p23);                      \
                acc[q].comp = fmaf(num, r, acc[q].comp);                         \
            }
            EVAL(x) EVAL(y) EVAL(z) EVAL(w)
            #undef EVAL
        }
    }

    if (uh) {
        #pragma unroll
        for (int q = 0; q < QB; ++q)
            scr[vt * QB + q] = acc[q];
    }
    __syncthreads();

    float4 e[QB];
    if (!uh) {
        #pragma unroll
        for (int q = 0; q < QB; ++q) {
            const float4 t = scr[vt * QB + q];
            acc[q].x += t.x; acc[q].y += t.y; acc[q].z += t.z; acc[q].w += t.w;
            e[q].x = fast_exp2(-2.f * LOG2E * acc[q].x);
            e[q].y = fast_exp2(-2.f * LOG2E * acc[q].y);
            e[q].z = fast_exp2(-2.f * LOG2E * acc[q].z);
            e[q].w = fast_exp2(-2.f * LOG2E * acc[q].w);
            float s = wave_sum((e[q].x + e[q].y) + (e[q].z + e[q].w));
            if (lane == 0) reds[q][wid] = s;
        }
    }
    __syncthreads();
    if (!uh) {
        #pragma unroll
        for (int q = 0; q < QB; ++q) {
            const float ss = (reds[q][0] + reds[q][1]) + (reds[q][2] + reds[q][3]);
            const float inv = __builtin_amdgcn_rcpf(ss);
            float4 o;
            o.x = e[q].x * inv; o.y = e[q].y * inv;
            o.z = e[q].z * inv; o.w = e[q].w * inv;
            *(float4*)(a_lds + q * TV + 4 * vt) = o;
            *(float4*)(out_attn + (size_t)(b * TQ + q0 + q) * TV + 4 * vt) = o;
        }
    }
    __syncthreads();

    // ---- phase B: thread owns (4 d-cols, QB q-rows, 128-v range) ----
    const int vq = tid >> 6;               // 0..7 -> v-range (one wave each)
    const int dp = tid & 63;               // d-quad index
    const int d0 = dp * 4;
    const unsigned short* vb = vbf + ((size_t)b * TV + vq * 128) * DV + d0;
    float4 c[QB];
    #pragma unroll
    for (int q = 0; q < QB; ++q) { c[q].x = c[q].y = c[q].z = c[q].w = 0.f; }

    #pragma unroll 2
    for (int v4 = 0; v4 < 32; ++v4) {
        const int v = vq * 128 + v4 * 4;
        const float4 a0 = *(const float4*)(a_lds + 0 * TV + v);
        const float4 a1 = *(const float4*)(a_lds + 1 * TV + v);
        const float4 a2 = *(const float4*)(a_lds + 2 * TV + v);
        const float4 a3 = *(const float4*)(a_lds + 3 * TV + v);
        #define STEP(j, comp)                                                    \
        {                                                                        \
            const ushort4 wv = *(const ushort4*)(vb + (size_t)(v4 * 4 + j) * DV);\
            const float v0 = __uint_as_float((unsigned)wv.x << 16);              \
            const float v1 = __uint_as_float((unsigned)wv.y << 16);              \
            const float v2 = __uint_as_float((unsigned)wv.z << 16);              \
            const float v3 = __uint_as_float((unsigned)wv.w << 16);              \
            c[0].x = fmaf(a0.comp, v0, c[0].x); c[0].y = fmaf(a0.comp, v1, c[0].y); \
            c[0].z = fmaf(a0.comp, v2, c[0].z); c[0].w = fmaf(a0.comp, v3, c[0].w); \
            c[1].x = fmaf(a1.comp, v0, c[1].x); c[1].y = fmaf(a1.comp, v1, c[1].y); \
            c[1].z = fmaf(a1.comp, v2, c[1].z); c[1].w = fmaf(a1.comp, v3, c[1].w); \
            c[2].x = fmaf(a2.comp, v0, c[2].x); c[2].y = fmaf(a2.comp, v1, c[2].y); \
            c[2].z = fmaf(a2.comp, v2, c[2].z); c[2].w = fmaf(a2.comp, v3, c[2].w); \
            c[3].x = fmaf(a3.comp, v0, c[3].x); c[3].y = fmaf(a3.comp, v1, c[3].y); \
            c[3].z = fmaf(a3.comp, v2, c[3].z); c[3].w = fmaf(a3.comp, v3, c[3].w); \
        }
        STEP(0, x) STEP(1, y) STEP(2, z) STEP(3, w)
        #undef STEP
    }
    __syncthreads();   // all a_lds reads done; reuse pool as reduce buffer

    // reduce partials across 8 v-groups (group 0 finishes); 7*4q*64dp*4 floats
    if (vq != 0) {
        float* r = pool + (size_t)(vq - 1) * (QB * 64 * 4) + (0 * 64 + dp) * 4;
        #pragma unroll
        for (int q = 0; q < QB; ++q)
            *(float4*)(r + q * 64 * 4) = c[q];
    }
    __syncthreads();
    if (vq == 0) {
        #pragma unroll
        for (int g = 0; g < 7; ++g) {
            const float* r = pool + (size_t)g * (QB * 64 * 4) + dp * 4;
            #pragma unroll
            for (int q = 0; q < QB; ++q) {
                const float4 t = *(const float4*)(r + q * 64 * 4);
                c[q].x += t.x; c[q].y += t.y; c[q].z += t.z; c[q].w += t.w;
            }
        }
        #pragma unroll
        for (int q = 0; q < QB; ++q)
            *(float4*)(out_ctx + (size_t)(b * TQ + q0 + q) * DV + d0) = c[q];
    }
}

extern "C" void kernel_launch(void* const* d_in, const int* in_sizes, int n_in,
                              void* d_out, int out_size, void* d_ws, size_t ws_size,
                              hipStream_t stream) {
    const float* query = (const float*)d_in[0];
    const float* value = (const float*)d_in[1];
    const float* w1    = (const float*)d_in[2];
    const float* w2    = (const float*)d_in[3];
    const float* scale = (const float*)d_in[4];

    float* out      = (float*)d_out;
    float* out_ctx  = out;                         // [NQROW*DV]
    float* out_attn = out + (size_t)NQROW * DV;    // [NQROW*TV]

    float* Eq  = (float*)d_ws;                         // NQROW*UNITS floats
    float* EkT = Eq + (size_t)NQROW * UNITS;           // UNITS*NKROW floats
    unsigned short* vbf = (unsigned short*)(EkT + (size_t)UNITS * NKROW);

    proj_kernel<<<dim3((NQROW + NKROW) / RPB), 256, 0, stream>>>(
        query, value, w1, w2, Eq, EkT, vbf);
    sc_kernel<<<dim3(NQROW / QB), 512, 0, stream>>>(
        Eq, EkT, scale, vbf, out_attn, out_ctx);
}